// Round 7
// baseline (744.841 us; speedup 1.0000x reference)
//
#include <hip/hip_runtime.h>
#include <math.h>

#define BGR 256        // graphs
#define NPG0 400       // nodes per graph
#define NN (BGR*NPG0)  // 102400 nodes
#define NE (NN*16)     // 1638400 edges
#define EPG (NPG0*16)  // 6400 edges per graph (contiguous in edge list)
#define HD 128
#define AST 416        // adjacency row stride (elements), K padded to 13*32
#define KSA 13         // agg k-steps (13*32 = 416)
#define XSTR 424       // XT LDS row stride (shorts)
#define MSTR 136       // mean LDS row stride (shorts)
#define SUSZ 54400     // union LDS shorts: max(128*424, 400*136)
#define QROWS 100      // adjacency-build rows per block

typedef __attribute__((ext_vector_type(8))) short short8;
typedef __attribute__((ext_vector_type(4))) float floatx4;

__device__ __forceinline__ unsigned short f2b(float f) {
    unsigned int u = __builtin_bit_cast(unsigned int, f);
    unsigned int r = (u + 0x7fffu + ((u >> 16) & 1u)) >> 16;
    return (unsigned short)r;
}
__device__ __forceinline__ unsigned int pk2(float a, float b) {
    return (unsigned int)f2b(a) | ((unsigned int)f2b(b) << 16);
}
__device__ __forceinline__ float b2f(unsigned short h) {
    return __builtin_bit_cast(float, (unsigned int)h << 16);
}
__device__ __forceinline__ float b2f_lo(unsigned int u) { return __builtin_bit_cast(float, u << 16); }
__device__ __forceinline__ float b2f_hi(unsigned int u) { return __builtin_bit_cast(float, u & 0xffff0000u); }
__device__ __forceinline__ unsigned short bfint(unsigned int v) {
    return (unsigned short)(__builtin_bit_cast(unsigned int, (float)v) >> 16);   // exact for v<256
}

// ---------------- adjacency build in LDS (bf16 out) + rliv/alive init
// block = (graph, dst-quarter); edges of graph g are contiguous [g*EPG, (g+1)*EPG)
__global__ __launch_bounds__(256) void k_abuild2(const int* __restrict__ src,
    const int* __restrict__ dst, unsigned short* __restrict__ Abf,
    float* __restrict__ alive, float* __restrict__ rliv) {
    __shared__ unsigned int sA[QROWS * AST / 2];   // u16 cells packed in u32
    int g = blockIdx.x >> 2, q = blockIdx.x & 3;
    int t = threadIdx.x;
    for (int i = t; i < QROWS * AST / 2; i += 256) sA[i] = 0;
    __syncthreads();
    int ebase = g * EPG, d0 = q * QROWS, gb = g * NPG0;
    for (int it = 0; it < EPG / 256; ++it) {
        int e = ebase + it * 256 + t;
        int s = src[e] - gb;
        int d = dst[e] - gb - d0;
        if ((unsigned)d < QROWS) {
            int idx = d * AST + s;
            atomicAdd(&sA[idx >> 1], 1u << ((idx & 1) * 16));
        }
    }
    __syncthreads();
    unsigned int* orow = (unsigned int*)(Abf + ((long)gb + d0) * AST);
    for (int i = t; i < QROWS * AST / 2; i += 256) {
        unsigned int w = sA[i];
        orow[i] = (unsigned int)bfint(w & 0xffffu) | ((unsigned int)bfint(w >> 16) << 16);
    }
    for (int r = t; r < QROWS; r += 256) {
        unsigned int sum = 0;
        for (int wd = 0; wd < AST / 2; ++wd) {
            unsigned int w = sA[r * (AST / 2) + wd];
            sum += (w & 0xffffu) + (w >> 16);
        }
        long o = (long)gb + d0 + r;
        rliv[o] = 1.0f / fmaxf((float)sum, 1.0f);
        alive[o] = 1.0f;
    }
}

// ---------------- W -> bf16, transposed
__global__ void k_wcvt(const float* __restrict__ c1_wr, const float* __restrict__ c1_ws,
                       const float* __restrict__ cs_wr, const float* __restrict__ cs_ws,
                       unsigned short* __restrict__ bt) {
    int m = blockIdx.y;
    int idx = blockIdx.x * 256 + threadIdx.x;
    const float* W = (m == 0) ? c1_wr : (m == 1) ? c1_ws
                   : (m < 6) ? (cs_wr + (m - 2) * HD * HD) : (cs_ws + (m - 6) * HD * HD);
    int n = idx >> 7, k = idx & 127;
    bt[m * HD * HD + idx] = f2b(W[k * HD + n]);
}

// ---------------- fused layer (one block/graph, 512 thr): agg GEMM (bf16 adjacency) + conv
// multg != nullptr: input x rows are scaled by multg (pending pool scale fold)
template<bool XF32>
__global__ __launch_bounds__(512, 2) void k_layer2(
    const void* __restrict__ xin_v, unsigned short* __restrict__ xout,
    const unsigned short* __restrict__ Abf,
    const float* __restrict__ alive, const float* __restrict__ rliv,
    const unsigned short* __restrict__ wr_bt, const unsigned short* __restrict__ ws_bt,
    const float* __restrict__ bias, float* __restrict__ hcat, int layer,
    const float* __restrict__ multg)
{
    __shared__ __align__(16) unsigned short sU[SUSZ];
    int g = blockIdx.x;
    int t = threadIdx.x;
    long gbase = (long)g * NPG0;

    // ---- phase 1: stage XT (4x4 shfl transpose), scaled by mult if present
    for (int it = 0; it < 25; ++it) {
        int task = it * 128 + (t >> 2);
        int j = t & 3;
        int r0 = (task >> 5) * 4;
        int f0 = (task & 31) * 4;
        float a0, a1, a2, a3;
        if (XF32) {
            float4 v = ((const float4*)xin_v)[(gbase + r0 + j) * 32 + (f0 >> 2)];
            a0 = v.x; a1 = v.y; a2 = v.z; a3 = v.w;
        } else {
            uint2 u = ((const uint2*)xin_v)[(gbase + r0 + j) * 32 + (f0 >> 2)];
            a0 = b2f_lo(u.x); a1 = b2f_hi(u.x); a2 = b2f_lo(u.y); a3 = b2f_hi(u.y);
        }
        if (multg) {
            float m = multg[gbase + r0 + j];
            a0 *= m; a1 *= m; a2 *= m; a3 *= m;
        }
        float tw;
        bool bo1 = j & 1;
        tw = __shfl_xor(bo1 ? a0 : a1, 1); if (bo1) a0 = tw; else a1 = tw;
        tw = __shfl_xor(bo1 ? a2 : a3, 1); if (bo1) a2 = tw; else a3 = tw;
        bool bo2 = (j & 2) != 0;
        tw = __shfl_xor(bo2 ? a0 : a2, 2); if (bo2) a0 = tw; else a2 = tw;
        tw = __shfl_xor(bo2 ? a1 : a3, 2); if (bo2) a1 = tw; else a3 = tw;
        uint2 w; w.x = pk2(a0, a1); w.y = pk2(a2, a3);
        *(uint2*)&sU[(f0 + j) * XSTR + r0] = w;
    }
    for (int idx = t; idx < HD * 16; idx += 512) {
        int f = idx >> 4, c = idx & 15;
        sU[f * XSTR + 400 + c] = 0;
    }
    __syncthreads();

    int lane = t & 63, wid = t >> 6;
    int quad = lane >> 4, l15 = lane & 15;
    int mp = wid & 3;
    int nh = wid >> 2;
    int ntB = nh ? 13 : 0;
    int ntE = nh ? 25 : 13;

    // ---- phase 2: preload agg A-frags (XT)
    short8 Afr[2][KSA];
#pragma unroll
    for (int mt = 0; mt < 2; ++mt)
#pragma unroll
        for (int k = 0; k < KSA; ++k)
            Afr[mt][k] = *(const short8*)&sU[((2 * mp + mt) * 16 + l15) * XSTR + k * 32 + quad * 8];
    __syncthreads();   // XT reads done; sU reused for mean

    // ---- phase 3: meanT = XT . A^T  (B = bf16 adjacency rows, b128 loads)
    const unsigned short* Ag = Abf + gbase * AST;
    for (int nt = ntB; nt < ntE; ++nt) {
        const unsigned short* Ar = Ag + (long)(nt * 16 + l15) * AST;
        floatx4 acc0 = {0.f, 0.f, 0.f, 0.f};
        floatx4 acc1 = {0.f, 0.f, 0.f, 0.f};
#pragma unroll
        for (int k = 0; k < KSA; ++k) {
            short8 Bf = *(const short8*)&Ar[k * 32 + quad * 8];
            acc0 = __builtin_amdgcn_mfma_f32_16x16x32_bf16(Afr[0][k], Bf, acc0, 0, 0, 0);
            acc1 = __builtin_amdgcn_mfma_f32_16x16x32_bf16(Afr[1][k], Bf, acc1, 0, 0, 0);
        }
        int o = nt * 16 + l15;
        float rl = rliv[gbase + o];
        unsigned short* mrow = &sU[o * MSTR + 32 * mp + quad * 4];
        uint2 w0, w1;
        w0.x = pk2(acc0[0] * rl, acc0[1] * rl); w0.y = pk2(acc0[2] * rl, acc0[3] * rl);
        w1.x = pk2(acc1[0] * rl, acc1[1] * rl); w1.y = pk2(acc1[2] * rl, acc1[3] * rl);
        *(uint2*)mrow = w0;
        *(uint2*)(mrow + 16) = w1;
    }
    __syncthreads();

    // ---- phase 4: OUT^T = WrT.meanT + WsT.xT + b
    short8 Wr8[2][4], Ws8[2][4];
#pragma unroll
    for (int mt = 0; mt < 2; ++mt) {
        int j = (2 * mp + mt) * 16 + l15;
#pragma unroll
        for (int k = 0; k < 4; ++k) {
            Wr8[mt][k] = *(const short8*)&wr_bt[j * HD + k * 32 + quad * 8];
            Ws8[mt][k] = *(const short8*)&ws_bt[j * HD + k * 32 + quad * 8];
        }
    }
    float4 b40 = *(const float4*)&bias[(2 * mp) * 16 + quad * 4];
    float4 b41 = *(const float4*)&bias[(2 * mp + 1) * 16 + quad * 4];
    float ps0[4] = {0, 0, 0, 0}, ps1[4] = {0, 0, 0, 0};

    for (int nt = ntB; nt < ntE; ++nt) {
        int o = nt * 16 + l15;
        long go = gbase + o;
        floatx4 a0 = {b40.x, b40.y, b40.z, b40.w};
        floatx4 a1 = {b41.x, b41.y, b41.z, b41.w};
#pragma unroll
        for (int k = 0; k < 4; ++k) {
            short8 B0 = *(const short8*)&sU[o * MSTR + k * 32 + quad * 8];
            a0 = __builtin_amdgcn_mfma_f32_16x16x32_bf16(Wr8[0][k], B0, a0, 0, 0, 0);
            a1 = __builtin_amdgcn_mfma_f32_16x16x32_bf16(Wr8[1][k], B0, a1, 0, 0, 0);
        }
        if (XF32) {
            const float4* xf = (const float4*)xin_v;
#pragma unroll
            for (int k = 0; k < 4; ++k) {
                float4 v0 = xf[go * 32 + k * 8 + quad * 2];
                float4 v1 = xf[go * 32 + k * 8 + quad * 2 + 1];
                short8 B1;
                B1[0] = (short)f2b(v0.x); B1[1] = (short)f2b(v0.y);
                B1[2] = (short)f2b(v0.z); B1[3] = (short)f2b(v0.w);
                B1[4] = (short)f2b(v1.x); B1[5] = (short)f2b(v1.y);
                B1[6] = (short)f2b(v1.z); B1[7] = (short)f2b(v1.w);
                a0 = __builtin_amdgcn_mfma_f32_16x16x32_bf16(Ws8[0][k], B1, a0, 0, 0, 0);
                a1 = __builtin_amdgcn_mfma_f32_16x16x32_bf16(Ws8[1][k], B1, a1, 0, 0, 0);
            }
        } else {
            const unsigned short* x16 = (const unsigned short*)xin_v;
            float m = multg ? multg[go] : 1.0f;
#pragma unroll
            for (int k = 0; k < 4; ++k) {
                short8 B1 = *(const short8*)&x16[go * HD + k * 32 + quad * 8];
                if (multg) {
#pragma unroll
                    for (int e = 0; e < 8; ++e)
                        B1[e] = (short)f2b(b2f((unsigned short)B1[e]) * m);
                }
                a0 = __builtin_amdgcn_mfma_f32_16x16x32_bf16(Ws8[0][k], B1, a0, 0, 0, 0);
                a1 = __builtin_amdgcn_mfma_f32_16x16x32_bf16(Ws8[1][k], B1, a1, 0, 0, 0);
            }
        }
        bool liv = alive[go] != 0.0f;
        float v0r[4], v1r[4];
#pragma unroll
        for (int rr = 0; rr < 4; ++rr) {
            v0r[rr] = fmaxf(a0[rr], 0.0f);
            v1r[rr] = fmaxf(a1[rr], 0.0f);
            if (liv) { ps0[rr] += v0r[rr]; ps1[rr] += v1r[rr]; }
            if (!liv) { v0r[rr] = 0.0f; v1r[rr] = 0.0f; }
        }
        unsigned short* orow = &xout[go * HD];
        uint2 w0, w1;
        w0.x = pk2(v0r[0], v0r[1]); w0.y = pk2(v0r[2], v0r[3]);
        w1.x = pk2(v1r[0], v1r[1]); w1.y = pk2(v1r[2], v1r[3]);
        *(uint2*)&orow[(2 * mp) * 16 + quad * 4] = w0;
        *(uint2*)&orow[(2 * mp + 1) * 16 + quad * 4] = w1;
    }
#pragma unroll
    for (int rr = 0; rr < 4; ++rr) {
        float v = ps0[rr];
        v += __shfl_xor(v, 1); v += __shfl_xor(v, 2); v += __shfl_xor(v, 4); v += __shfl_xor(v, 8);
        float u = ps1[rr];
        u += __shfl_xor(u, 1); u += __shfl_xor(u, 2); u += __shfl_xor(u, 4); u += __shfl_xor(u, 8);
        if (l15 == 0) {
            atomicAdd(&hcat[g * (5 * HD) + layer * HD + (2 * mp) * 16 + quad * 4 + rr], v);
            atomicAdd(&hcat[g * (5 * HD) + layer * HD + (2 * mp + 1) * 16 + quad * 4 + rr], u);
        }
    }
}

// ---------------- pool dots (massively parallel): tr = x.wr ; tsb = x.ws + b
__global__ __launch_bounds__(256) void k_dots(const unsigned short* __restrict__ x,
    const float* __restrict__ wr, const float* __restrict__ ws, const float* __restrict__ pb,
    float* __restrict__ tr, float* __restrict__ tsb) {
    int lane = threadIdx.x;
    int o = blockIdx.x * 8 + threadIdx.y;
    uint2 u = ((const uint2*)x)[(long)o * 32 + lane];
    float x0 = b2f_lo(u.x), x1 = b2f_hi(u.x), x2 = b2f_lo(u.y), x3 = b2f_hi(u.y);
    float4 w1 = ((const float4*)wr)[lane];
    float4 w2 = ((const float4*)ws)[lane];
    float a = x0 * w1.x + x1 * w1.y + x2 * w1.z + x3 * w1.w;
    float c = x0 * w2.x + x1 * w2.y + x2 * w2.z + x3 * w2.w;
#pragma unroll
    for (int m = 1; m < 32; m <<= 1) { a += __shfl_xor(a, m); c += __shfl_xor(c, m); }
    if (lane == 0) { tr[o] = a; tsb[o] = c + pb[0]; }
}

// ---------------- top-K (x-free): dense score dot, bitonic sort, keep, mult/alive/rliv
__global__ __launch_bounds__(256) void k_topk(const unsigned short* __restrict__ Abf,
    const float* __restrict__ trb, const float* __restrict__ tsbb,
    float* __restrict__ alive, float* __restrict__ rliv,
    float* __restrict__ multg, int K)
{
    __shared__ float str[NPG0];
    __shared__ float skf[NPG0];
    __shared__ float s[512];
    __shared__ float sc[NPG0];
    __shared__ unsigned char keep[NPG0];
    __shared__ int cnt_gt;
    int g = blockIdx.x, t = threadIdx.x;
    long nb = (long)g * NPG0;

    for (int n = t; n < NPG0; n += 256) str[n] = trb[nb + n];
    if (t == 0) cnt_gt = 0;
    __syncthreads();

    // score: (A . tr) * rliv + tsb  (LDS same-address broadcast on str)
    for (int n = t; n < 512; n += 256) {
        float v = -INFINITY;
        if (n < NPG0 && alive[nb + n] != 0.0f) {
            const unsigned int* Ar = (const unsigned int*)(Abf + (nb + n) * AST);
            float acc = 0.0f;
            const float2* tp = (const float2*)str;
            for (int w = 0; w < 200; ++w) {
                unsigned int a = Ar[w];
                float2 tv = tp[w];
                acc = fmaf(b2f_lo(a), tv.x, acc);
                acc = fmaf(b2f_hi(a), tv.y, acc);
            }
            v = acc * rliv[nb + n] + tsbb[nb + n];
        }
        s[n] = v;
        if (n < NPG0) sc[n] = v;
    }
    __syncthreads();

    for (int ksz = 2; ksz <= 512; ksz <<= 1) {
        for (int jsz = ksz >> 1; jsz >= 1; jsz >>= 1) {
            for (int i = t; i < 512; i += 256) {
                int ixj = i ^ jsz;
                if (ixj > i) {
                    float a = s[i], c = s[ixj];
                    bool up = ((i & ksz) == 0);
                    if ((a > c) == up) { s[i] = c; s[ixj] = a; }
                }
            }
            __syncthreads();
        }
    }
    float thr = s[512 - K];
    for (int n = t; n < NPG0; n += 256)
        if (sc[n] > thr) atomicAdd(&cnt_gt, 1);
    __syncthreads();
    if (t == 0) {   // tie-break: lowest index (matches lax.top_k)
        int m = K - cnt_gt, tk = 0;
        for (int n = 0; n < NPG0; n++) {
            bool kp = sc[n] > thr;
            if (!kp && sc[n] == thr && tk < m) { kp = true; tk++; }
            keep[n] = kp ? 1 : 0;
        }
    }
    __syncthreads();
    for (int n = t; n < NPG0; n += 256) {
        bool kp = keep[n] != 0;
        multg[nb + n] = kp ? tanhf(sc[n]) : 0.0f;
        alive[nb + n] = kp ? 1.0f : 0.0f;
        skf[n] = kp ? 1.0f : 0.0f;
    }
    __syncthreads();
    // rliv update: alive in-degree = A . keep
    for (int n = t; n < NPG0; n += 256) {
        const unsigned int* Ar = (const unsigned int*)(Abf + (nb + n) * AST);
        const float2* kp2 = (const float2*)skf;
        float acc = 0.0f;
        for (int w = 0; w < 200; ++w) {
            unsigned int a = Ar[w];
            float2 kv = kp2[w];
            acc = fmaf(b2f_lo(a), kv.x, acc);
            acc = fmaf(b2f_hi(a), kv.y, acc);
        }
        rliv[nb + n] = 1.0f / fmaxf(acc, 1.0f);
    }
}

// ---------------- final MLP + log_softmax (hcat holds SUMS; divide here)
__global__ __launch_bounds__(256) void k_mlp(const float* __restrict__ h, const float* __restrict__ w1,
    const float* __restrict__ b1, const float* __restrict__ w2,
    const float* __restrict__ b2, float* __restrict__ out) {
    __shared__ float shg[5 * HD];
    __shared__ float prt[256];
    __shared__ float h1[HD];
    __shared__ float red[HD];
    __shared__ float lg[2];
    const float inv[5] = {1.0f/400.0f, 1.0f/400.0f, 1.0f/320.0f, 1.0f/320.0f, 1.0f/256.0f};
    int g = blockIdx.x, t = threadIdx.x;
    for (int k = t; k < 5 * HD; k += 256) shg[k] = h[g * (5 * HD) + k] * inv[k >> 7];
    __syncthreads();
    int j = t & 127, half = t >> 7;
    float acc = half ? 0.0f : b1[j];
    for (int k = half * 320; k < half * 320 + 320; ++k)
        acc = fmaf(shg[k], w1[k * HD + j], acc);
    prt[t] = acc;
    __syncthreads();
    if (t < HD) h1[t] = fmaxf(prt[t] + prt[t + 128], 0.0f);
    __syncthreads();
    for (int c = 0; c < 2; c++) {
        if (t < HD) red[t] = h1[t] * w2[t * 2 + c];
        __syncthreads();
        for (int st = 64; st > 0; st >>= 1) {
            if (t < st) red[t] += red[t + st];
            __syncthreads();
        }
        if (t == 0) lg[c] = red[0] + b2[c];
        __syncthreads();
    }
    if (t == 0) {
        float l0 = lg[0], l1 = lg[1];
        float m = fmaxf(l0, l1);
        float lse = m + logf(expf(l0 - m) + expf(l1 - m));
        out[g * 2 + 0] = l0 - lse;
        out[g * 2 + 1] = l1 - lse;
    }
}

extern "C" void kernel_launch(void* const* d_in, const int* in_sizes, int n_in,
                              void* d_out, int out_size, void* d_ws, size_t ws_size,
                              hipStream_t stream) {
    const float* x_in   = (const float*)d_in[0];
    const int*   eidx   = (const int*)d_in[1];
    const int*   e_src  = eidx;
    const int*   e_dst  = eidx + NE;
    const float* c1_wr  = (const float*)d_in[3];
    const float* c1_ws  = (const float*)d_in[4];
    const float* c1_b   = (const float*)d_in[5];
    const float* cs_wr  = (const float*)d_in[6];
    const float* cs_ws  = (const float*)d_in[7];
    const float* cs_b   = (const float*)d_in[8];
    const float* p_wr   = (const float*)d_in[9];
    const float* p_ws   = (const float*)d_in[10];
    const float* p_b    = (const float*)d_in[11];
    const float* l1_w   = (const float*)d_in[12];
    const float* l1_b   = (const float*)d_in[13];
    const float* l2_w   = (const float*)d_in[14];
    const float* l2_b   = (const float*)d_in[15];
    float* out = (float*)d_out;

    char* ws = (char*)d_ws;
    size_t off = 0;
    float* alive = (float*)(ws + off);                 off += (size_t)NN * 4;
    float* rliv  = (float*)(ws + off);                 off += (size_t)NN * 4;
    unsigned short* xb0 = (unsigned short*)(ws + off); off += (size_t)NN * HD * 2;
    unsigned short* xb1 = (unsigned short*)(ws + off); off += (size_t)NN * HD * 2;
    float* hcat  = (float*)(ws + off);                 off += (size_t)BGR * 5 * HD * 4;
    unsigned short* wbt = (unsigned short*)(ws + off); off += (size_t)10 * HD * HD * 2;
    unsigned short* Abf = (unsigned short*)(ws + off); off += (size_t)NN * AST * 2;
    float* trb   = (float*)(ws + off);                 off += (size_t)NN * 4;
    float* tsbb  = (float*)(ws + off);                 off += (size_t)NN * 4;
    float* multb = (float*)(ws + off);                 off += (size_t)NN * 4;

    hipMemsetAsync(hcat, 0, (size_t)BGR * 5 * HD * 4, stream);
    k_abuild2<<<BGR * 4, 256, 0, stream>>>(e_src, e_dst, Abf, alive, rliv);
    k_wcvt<<<dim3(64, 10), 256, 0, stream>>>(c1_wr, c1_ws, cs_wr, cs_ws, wbt);

    unsigned short* bt_wr[5] = { wbt + 0 * HD * HD, wbt + 2 * HD * HD, wbt + 3 * HD * HD, wbt + 4 * HD * HD, wbt + 5 * HD * HD };
    unsigned short* bt_ws[5] = { wbt + 1 * HD * HD, wbt + 6 * HD * HD, wbt + 7 * HD * HD, wbt + 8 * HD * HD, wbt + 9 * HD * HD };
    dim3 dotsB(32, 8);

    // conv1: x_in(fp32) -> xb0
    k_layer2<true><<<BGR, 512, 0, stream>>>(x_in, xb0, Abf, alive, rliv,
                                            bt_wr[0], bt_ws[0], c1_b, hcat, 0, nullptr);
    // convs[0]: xb0 -> xb1
    k_layer2<false><<<BGR, 512, 0, stream>>>(xb0, xb1, Abf, alive, rliv,
                                             bt_wr[1], bt_ws[1], cs_b + 0 * HD, hcat, 1, nullptr);
    // pool 0 (K=320) on xb1: dots + topk (scale folded into next layer)
    k_dots<<<NN / 8, dotsB, 0, stream>>>(xb1, p_wr + 0 * HD, p_ws + 0 * HD, p_b + 0, trb, tsbb);
    k_topk<<<BGR, 256, 0, stream>>>(Abf, trb, tsbb, alive, rliv, multb, 320);
    // convs[1]: xb1 -> xb0 (applies mult)
    k_layer2<false><<<BGR, 512, 0, stream>>>(xb1, xb0, Abf, alive, rliv,
                                             bt_wr[2], bt_ws[2], cs_b + 1 * HD, hcat, 2, multb);
    // convs[2]: xb0 -> xb1
    k_layer2<false><<<BGR, 512, 0, stream>>>(xb0, xb1, Abf, alive, rliv,
                                             bt_wr[3], bt_ws[3], cs_b + 2 * HD, hcat, 3, nullptr);
    // pool 1 (K=256) on xb1
    k_dots<<<NN / 8, dotsB, 0, stream>>>(xb1, p_wr + 1 * HD, p_ws + 1 * HD, p_b + 1, trb, tsbb);
    k_topk<<<BGR, 256, 0, stream>>>(Abf, trb, tsbb, alive, rliv, multb, 256);
    // convs[3]: xb1 -> xb0 (applies mult)
    k_layer2<false><<<BGR, 512, 0, stream>>>(xb1, xb0, Abf, alive, rliv,
                                             bt_wr[4], bt_ws[4], cs_b + 3 * HD, hcat, 4, multb);
    // MLP head
    k_mlp<<<BGR, 256, 0, stream>>>(hcat, l1_w, l1_b, l2_w, l2_b, out);
}